// Round 1
// baseline (642.379 us; speedup 1.0000x reference)
//
#include <hip/hip_runtime.h>

#define NN 50000
#define NE 400000
#define NBATCH 8
#define DD 128

typedef unsigned short u16;
typedef __attribute__((ext_vector_type(8))) short bf16x8;
typedef __attribute__((ext_vector_type(8))) unsigned short u16x8;
typedef __attribute__((ext_vector_type(4))) float f32x4;

__device__ __forceinline__ u16 f2bf(float f) {
  union { float f; unsigned u; } a; a.f = f;
  unsigned r = a.u + 0x7fffu + ((a.u >> 16) & 1u);
  return (u16)(r >> 16);
}

__device__ __forceinline__ u16x8 cvt8(const float* p) {
  f32x4 a = *(const f32x4*)p;
  f32x4 b = *(const f32x4*)(p + 4);
  u16x8 r;
  r[0]=f2bf(a[0]); r[1]=f2bf(a[1]); r[2]=f2bf(a[2]); r[3]=f2bf(a[3]);
  r[4]=f2bf(b[0]); r[5]=f2bf(b[1]); r[6]=f2bf(b[2]); r[7]=f2bf(b[3]);
  return r;
}

// Convert+transpose fp32 weight [K][128] -> bf16 chunked [K/128][128 n][128 k]
__global__ void wconv_kernel(const float* __restrict__ src, u16* __restrict__ dst, int K) {
  int idx = blockIdx.x * 256 + threadIdx.x;
  if (idx >= K * 128) return;
  int k = idx >> 7, n = idx & 127;
  dst[((k >> 7) << 14) + (n << 7) + (k & 127)] = f2bf(src[idx]);
}

__global__ void xconv_kernel(const float* __restrict__ x, u16* __restrict__ xbf, int total4) {
  int i = blockIdx.x * 256 + threadIdx.x;
  if (i >= total4) return;
  f32x4 v = ((const f32x4*)x)[i];
  u16x8 dummy; // unused
  (void)dummy;
  u16 o0 = f2bf(v[0]), o1 = f2bf(v[1]), o2 = f2bf(v[2]), o3 = f2bf(v[3]);
  typedef __attribute__((ext_vector_type(4))) unsigned short u16x4;
  u16x4 o; o[0]=o0; o[1]=o1; o[2]=o2; o[3]=o3;
  ((u16x4*)xbf)[i] = o;
}

// ---------------- Edge MLP kernel: tile = 128 edges ----------------
__global__ __launch_bounds__(256, 2) void edge_kernel(
    const u16* __restrict__ xbf, const float* __restrict__ edge_attr,
    const float* __restrict__ u, const int* __restrict__ edge_index,
    const int* __restrict__ batch,
    const u16* __restrict__ w1, const u16* __restrict__ w2, const u16* __restrict__ w3,
    const float* __restrict__ b1, const float* __restrict__ b2, const float* __restrict__ b3,
    float* __restrict__ edge_out, float* agg,
    float* __restrict__ esum, unsigned* __restrict__ ecnt)
{
  __shared__ u16 As[128][136];
  __shared__ u16 Bs[128][136];
  __shared__ float red[NBATCH][128];
  __shared__ int rows_s[128], cols_s[128], ebat_s[128];
  __shared__ unsigned cnt8[NBATCH];

  const int tid = threadIdx.x;
  const int lane = tid & 63;
  const int wave = tid >> 6;
  const int wr = wave >> 1, wc = wave & 1;
  const int lr = lane & 15;
  const int lkb = lane >> 4;
  const int e0 = blockIdx.x * 128;

  if (tid < 128) {
    int r = edge_index[e0 + tid];
    int c = edge_index[NE + e0 + tid];
    rows_s[tid] = r; cols_s[tid] = c;
    ebat_s[tid] = batch[r];
  }
  for (int i = tid; i < NBATCH * 128; i += 256) (&red[0][0])[i] = 0.f;
  if (tid < NBATCH) cnt8[tid] = 0;

  f32x4 acc[4][4];
#pragma unroll
  for (int m = 0; m < 4; ++m)
#pragma unroll
    for (int n = 0; n < 4; ++n) { acc[m][n][0]=0.f; acc[m][n][1]=0.f; acc[m][n][2]=0.f; acc[m][n][3]=0.f; }

  __syncthreads();

  // ---- layer 1: K=512, 4 chunks of 128
  for (int c = 0; c < 4; ++c) {
    for (int i = tid; i < 128 * 16; i += 256) {
      int r = i >> 4, q = (i & 15) << 3;
      u16x8 v;
      if (c == 0)      v = *(const u16x8*)(xbf + (size_t)rows_s[r] * DD + q);
      else if (c == 1) v = *(const u16x8*)(xbf + (size_t)cols_s[r] * DD + q);
      else if (c == 2) v = cvt8(edge_attr + (size_t)(e0 + r) * DD + q);
      else             v = cvt8(u + (size_t)ebat_s[r] * DD + q);
      *(u16x8*)&As[r][q] = v;
      *(u16x8*)&Bs[r][q] = *(const u16x8*)(w1 + (c << 14) + (r << 7) + q);
    }
    __syncthreads();
#pragma unroll
    for (int kk = 0; kk < 4; ++kk) {
      bf16x8 af[4], bfr[4];
#pragma unroll
      for (int m = 0; m < 4; ++m) af[m] = *(const bf16x8*)&As[wr * 64 + m * 16 + lr][kk * 32 + lkb * 8];
#pragma unroll
      for (int n = 0; n < 4; ++n) bfr[n] = *(const bf16x8*)&Bs[wc * 64 + n * 16 + lr][kk * 32 + lkb * 8];
#pragma unroll
      for (int m = 0; m < 4; ++m)
#pragma unroll
        for (int n = 0; n < 4; ++n)
          acc[m][n] = __builtin_amdgcn_mfma_f32_16x16x32_bf16(af[m], bfr[n], acc[m][n], 0, 0, 0);
    }
    __syncthreads();
  }

  // epilogue 1: h1 = relu(acc + b1) -> As ; stage w2 -> Bs
#pragma unroll
  for (int n = 0; n < 4; ++n) {
    int colg = wc * 64 + n * 16 + lr;
    float bias = b1[colg];
#pragma unroll
    for (int m = 0; m < 4; ++m)
#pragma unroll
      for (int r = 0; r < 4; ++r) {
        int rowg = wr * 64 + m * 16 + lkb * 4 + r;
        float v = acc[m][n][r] + bias;
        v = v > 0.f ? v : 0.f;
        As[rowg][colg] = f2bf(v);
        acc[m][n][r] = 0.f;
      }
  }
  for (int i = tid; i < 128 * 16; i += 256) {
    int r = i >> 4, q = (i & 15) << 3;
    *(u16x8*)&Bs[r][q] = *(const u16x8*)(w2 + (r << 7) + q);
  }
  __syncthreads();

  // layer 2
#pragma unroll
  for (int kk = 0; kk < 4; ++kk) {
    bf16x8 af[4], bfr[4];
#pragma unroll
    for (int m = 0; m < 4; ++m) af[m] = *(const bf16x8*)&As[wr * 64 + m * 16 + lr][kk * 32 + lkb * 8];
#pragma unroll
    for (int n = 0; n < 4; ++n) bfr[n] = *(const bf16x8*)&Bs[wc * 64 + n * 16 + lr][kk * 32 + lkb * 8];
#pragma unroll
    for (int m = 0; m < 4; ++m)
#pragma unroll
      for (int n = 0; n < 4; ++n)
        acc[m][n] = __builtin_amdgcn_mfma_f32_16x16x32_bf16(af[m], bfr[n], acc[m][n], 0, 0, 0);
  }
  __syncthreads();

  // epilogue 2: h2 -> As ; stage w3 -> Bs
#pragma unroll
  for (int n = 0; n < 4; ++n) {
    int colg = wc * 64 + n * 16 + lr;
    float bias = b2[colg];
#pragma unroll
    for (int m = 0; m < 4; ++m)
#pragma unroll
      for (int r = 0; r < 4; ++r) {
        int rowg = wr * 64 + m * 16 + lkb * 4 + r;
        float v = acc[m][n][r] + bias;
        v = v > 0.f ? v : 0.f;
        As[rowg][colg] = f2bf(v);
        acc[m][n][r] = 0.f;
      }
  }
  for (int i = tid; i < 128 * 16; i += 256) {
    int r = i >> 4, q = (i & 15) << 3;
    *(u16x8*)&Bs[r][q] = *(const u16x8*)(w3 + (r << 7) + q);
  }
  __syncthreads();

  // layer 3
#pragma unroll
  for (int kk = 0; kk < 4; ++kk) {
    bf16x8 af[4], bfr[4];
#pragma unroll
    for (int m = 0; m < 4; ++m) af[m] = *(const bf16x8*)&As[wr * 64 + m * 16 + lr][kk * 32 + lkb * 8];
#pragma unroll
    for (int n = 0; n < 4; ++n) bfr[n] = *(const bf16x8*)&Bs[wc * 64 + n * 16 + lr][kk * 32 + lkb * 8];
#pragma unroll
    for (int m = 0; m < 4; ++m)
#pragma unroll
      for (int n = 0; n < 4; ++n)
        acc[m][n] = __builtin_amdgcn_mfma_f32_16x16x32_bf16(af[m], bfr[n], acc[m][n], 0, 0, 0);
  }

  // epilogue 3: edge_out + scatter-add agg + per-graph mean partials
#pragma unroll
  for (int n = 0; n < 4; ++n) {
    int colg = wc * 64 + n * 16 + lr;
    float bias = b3[colg];
#pragma unroll
    for (int m = 0; m < 4; ++m)
#pragma unroll
      for (int r = 0; r < 4; ++r) {
        int rowg = wr * 64 + m * 16 + lkb * 4 + r;
        float v = acc[m][n][r] + bias;
        edge_out[(size_t)(e0 + rowg) * DD + colg] = v;
        atomicAdd(&agg[(size_t)cols_s[rowg] * DD + colg], v);
        atomicAdd(&red[ebat_s[rowg]][colg], v);
      }
  }
  if (tid < 128) atomicAdd(&cnt8[ebat_s[tid]], 1u);
  __syncthreads();
  for (int i = tid; i < NBATCH * 128; i += 256) atomicAdd(&esum[i], (&red[0][0])[i]);
  if (tid < NBATCH) atomicAdd(&ecnt[tid], cnt8[tid]);
}

// ---------------- Node MLP kernel: tile = 128 nodes ----------------
__global__ __launch_bounds__(256, 2) void node_kernel(
    const u16* __restrict__ xbf, float* aggx /* agg in, x_out out (same region) */,
    const float* __restrict__ u, const int* __restrict__ batch,
    const u16* __restrict__ w1, const u16* __restrict__ w2, const u16* __restrict__ w3,
    const float* __restrict__ b1, const float* __restrict__ b2, const float* __restrict__ b3,
    float* __restrict__ nsum, unsigned* __restrict__ ncnt)
{
  __shared__ u16 As[128][136];
  __shared__ u16 Bs[128][136];
  __shared__ float red[NBATCH][128];
  __shared__ int nbat_s[128];
  __shared__ unsigned cnt8[NBATCH];

  const int tid = threadIdx.x;
  const int lane = tid & 63;
  const int wave = tid >> 6;
  const int wr = wave >> 1, wc = wave & 1;
  const int lr = lane & 15;
  const int lkb = lane >> 4;
  const int n0 = blockIdx.x * 128;

  if (tid < 128) {
    int node = n0 + tid;
    nbat_s[tid] = (node < NN) ? batch[node] : 0;
  }
  for (int i = tid; i < NBATCH * 128; i += 256) (&red[0][0])[i] = 0.f;
  if (tid < NBATCH) cnt8[tid] = 0;

  f32x4 acc[4][4];
#pragma unroll
  for (int m = 0; m < 4; ++m)
#pragma unroll
    for (int n = 0; n < 4; ++n) { acc[m][n][0]=0.f; acc[m][n][1]=0.f; acc[m][n][2]=0.f; acc[m][n][3]=0.f; }

  __syncthreads();

  // ---- layer 1: K=384, 3 chunks (x | agg | u[batch])
  for (int c = 0; c < 3; ++c) {
    for (int i = tid; i < 128 * 16; i += 256) {
      int r = i >> 4, q = (i & 15) << 3;
      int node = n0 + r;
      u16x8 v;
      if (node >= NN) { v[0]=0;v[1]=0;v[2]=0;v[3]=0;v[4]=0;v[5]=0;v[6]=0;v[7]=0; }
      else if (c == 0) v = *(const u16x8*)(xbf + (size_t)node * DD + q);
      else if (c == 1) v = cvt8(aggx + (size_t)node * DD + q);
      else             v = cvt8(u + (size_t)nbat_s[r] * DD + q);
      *(u16x8*)&As[r][q] = v;
      *(u16x8*)&Bs[r][q] = *(const u16x8*)(w1 + (c << 14) + (r << 7) + q);
    }
    __syncthreads();
#pragma unroll
    for (int kk = 0; kk < 4; ++kk) {
      bf16x8 af[4], bfr[4];
#pragma unroll
      for (int m = 0; m < 4; ++m) af[m] = *(const bf16x8*)&As[wr * 64 + m * 16 + lr][kk * 32 + lkb * 8];
#pragma unroll
      for (int n = 0; n < 4; ++n) bfr[n] = *(const bf16x8*)&Bs[wc * 64 + n * 16 + lr][kk * 32 + lkb * 8];
#pragma unroll
      for (int m = 0; m < 4; ++m)
#pragma unroll
        for (int n = 0; n < 4; ++n)
          acc[m][n] = __builtin_amdgcn_mfma_f32_16x16x32_bf16(af[m], bfr[n], acc[m][n], 0, 0, 0);
    }
    __syncthreads();
  }

  // epilogue 1
#pragma unroll
  for (int n = 0; n < 4; ++n) {
    int colg = wc * 64 + n * 16 + lr;
    float bias = b1[colg];
#pragma unroll
    for (int m = 0; m < 4; ++m)
#pragma unroll
      for (int r = 0; r < 4; ++r) {
        int rowg = wr * 64 + m * 16 + lkb * 4 + r;
        float v = acc[m][n][r] + bias;
        v = v > 0.f ? v : 0.f;
        As[rowg][colg] = f2bf(v);
        acc[m][n][r] = 0.f;
      }
  }
  for (int i = tid; i < 128 * 16; i += 256) {
    int r = i >> 4, q = (i & 15) << 3;
    *(u16x8*)&Bs[r][q] = *(const u16x8*)(w2 + (r << 7) + q);
  }
  __syncthreads();

  // layer 2
#pragma unroll
  for (int kk = 0; kk < 4; ++kk) {
    bf16x8 af[4], bfr[4];
#pragma unroll
    for (int m = 0; m < 4; ++m) af[m] = *(const bf16x8*)&As[wr * 64 + m * 16 + lr][kk * 32 + lkb * 8];
#pragma unroll
    for (int n = 0; n < 4; ++n) bfr[n] = *(const bf16x8*)&Bs[wc * 64 + n * 16 + lr][kk * 32 + lkb * 8];
#pragma unroll
    for (int m = 0; m < 4; ++m)
#pragma unroll
      for (int n = 0; n < 4; ++n)
        acc[m][n] = __builtin_amdgcn_mfma_f32_16x16x32_bf16(af[m], bfr[n], acc[m][n], 0, 0, 0);
  }
  __syncthreads();

  // epilogue 2
#pragma unroll
  for (int n = 0; n < 4; ++n) {
    int colg = wc * 64 + n * 16 + lr;
    float bias = b2[colg];
#pragma unroll
    for (int m = 0; m < 4; ++m)
#pragma unroll
      for (int r = 0; r < 4; ++r) {
        int rowg = wr * 64 + m * 16 + lkb * 4 + r;
        float v = acc[m][n][r] + bias;
        v = v > 0.f ? v : 0.f;
        As[rowg][colg] = f2bf(v);
        acc[m][n][r] = 0.f;
      }
  }
  for (int i = tid; i < 128 * 16; i += 256) {
    int r = i >> 4, q = (i & 15) << 3;
    *(u16x8*)&Bs[r][q] = *(const u16x8*)(w3 + (r << 7) + q);
  }
  __syncthreads();

  // layer 3
#pragma unroll
  for (int kk = 0; kk < 4; ++kk) {
    bf16x8 af[4], bfr[4];
#pragma unroll
    for (int m = 0; m < 4; ++m) af[m] = *(const bf16x8*)&As[wr * 64 + m * 16 + lr][kk * 32 + lkb * 8];
#pragma unroll
    for (int n = 0; n < 4; ++n) bfr[n] = *(const bf16x8*)&Bs[wc * 64 + n * 16 + lr][kk * 32 + lkb * 8];
#pragma unroll
    for (int m = 0; m < 4; ++m)
#pragma unroll
      for (int n = 0; n < 4; ++n)
        acc[m][n] = __builtin_amdgcn_mfma_f32_16x16x32_bf16(af[m], bfr[n], acc[m][n], 0, 0, 0);
  }

  // epilogue 3: x_out (overwrites agg region for this block's rows) + node-mean partials
#pragma unroll
  for (int n = 0; n < 4; ++n) {
    int colg = wc * 64 + n * 16 + lr;
    float bias = b3[colg];
#pragma unroll
    for (int m = 0; m < 4; ++m)
#pragma unroll
      for (int r = 0; r < 4; ++r) {
        int rowg = wr * 64 + m * 16 + lkb * 4 + r;
        int node = n0 + rowg;
        if (node < NN) {
          float v = acc[m][n][r] + bias;
          aggx[(size_t)node * DD + colg] = v;
          atomicAdd(&red[nbat_s[rowg]][colg], v);
        }
      }
  }
  if (tid < 128 && (n0 + tid) < NN) atomicAdd(&cnt8[nbat_s[tid]], 1u);
  __syncthreads();
  for (int i = tid; i < NBATCH * 128; i += 256) atomicAdd(&nsum[i], (&red[0][0])[i]);
  if (tid < NBATCH) atomicAdd(&ncnt[tid], cnt8[tid]);
}

// ---------------- Global MLP (fp32, tiny) ----------------
__global__ void global_kernel(
    const float* __restrict__ u,
    const float* __restrict__ nsum, const unsigned* __restrict__ ncnt,
    const float* __restrict__ esum, const unsigned* __restrict__ ecnt,
    const float* __restrict__ gW1, const float* __restrict__ gb1,
    const float* __restrict__ gW2, const float* __restrict__ gb2,
    const float* __restrict__ gW3, const float* __restrict__ gb3,
    float* __restrict__ u_out)
{
  __shared__ float gin[NBATCH][384];
  __shared__ float h1[NBATCH][128];
  __shared__ float h2[NBATCH][128];
  int tid = threadIdx.x;
  for (int i = tid; i < NBATCH * 128; i += 256) {
    int r = i >> 7, c = i & 127;
    float nc = (float)(ncnt[r] < 1u ? 1u : ncnt[r]);
    float ec = (float)(ecnt[r] < 1u ? 1u : ecnt[r]);
    gin[r][c] = u[i];
    gin[r][128 + c] = nsum[i] / nc;
    gin[r][256 + c] = esum[i] / ec;
  }
  __syncthreads();
  for (int o = tid; o < NBATCH * 128; o += 256) {
    int r = o >> 7, n = o & 127;
    float s = gb1[n];
    for (int k = 0; k < 384; ++k) s += gin[r][k] * gW1[k * 128 + n];
    h1[r][n] = fmaxf(s, 0.f);
  }
  __syncthreads();
  for (int o = tid; o < NBATCH * 128; o += 256) {
    int r = o >> 7, n = o & 127;
    float s = gb2[n];
    for (int k = 0; k < 128; ++k) s += h1[r][k] * gW2[k * 128 + n];
    h2[r][n] = fmaxf(s, 0.f);
  }
  __syncthreads();
  for (int o = tid; o < NBATCH * 128; o += 256) {
    int r = o >> 7, n = o & 127;
    float s = gb3[n];
    for (int k = 0; k < 128; ++k) s += h2[r][k] * gW3[k * 128 + n];
    u_out[o] = s;
  }
}

extern "C" void kernel_launch(void* const* d_in, const int* in_sizes, int n_in,
                              void* d_out, int out_size, void* d_ws, size_t ws_size,
                              hipStream_t stream) {
  const float* x          = (const float*)d_in[0];
  const int*   edge_index = (const int*)d_in[1];
  const float* edge_attr  = (const float*)d_in[2];
  const float* u          = (const float*)d_in[3];
  const int*   batch      = (const int*)d_in[4];
  const float* eW1 = (const float*)d_in[5];  const float* eb1 = (const float*)d_in[6];
  const float* eW2 = (const float*)d_in[7];  const float* eb2 = (const float*)d_in[8];
  const float* eW3 = (const float*)d_in[9];  const float* eb3 = (const float*)d_in[10];
  const float* nW1 = (const float*)d_in[11]; const float* nb1 = (const float*)d_in[12];
  const float* nW2 = (const float*)d_in[13]; const float* nb2 = (const float*)d_in[14];
  const float* nW3 = (const float*)d_in[15]; const float* nb3 = (const float*)d_in[16];
  const float* gW1 = (const float*)d_in[17]; const float* gb1 = (const float*)d_in[18];
  const float* gW2 = (const float*)d_in[19]; const float* gb2 = (const float*)d_in[20];
  const float* gW3 = (const float*)d_in[21]; const float* gb3 = (const float*)d_in[22];

  float* out      = (float*)d_out;
  float* xout_agg = out;                                  // [NN][128]: agg then x_out
  float* edge_out = out + (size_t)NN * DD;                // [NE][128]
  float* u_out    = out + (size_t)(NN + NE) * DD;         // [8][128]

  char* ws = (char*)d_ws;
  u16* wE1t = (u16*)(ws + 0);        // 4*128*128
  u16* wE2t = (u16*)(ws + 131072);   // 128*128
  u16* wE3t = (u16*)(ws + 163840);
  u16* wN1t = (u16*)(ws + 196608);   // 3*128*128
  u16* wN2t = (u16*)(ws + 294912);
  u16* wN3t = (u16*)(ws + 327680);
  u16* xbf  = (u16*)(ws + 524288);   // NN*128 bf16
  float* esum = (float*)(ws + 13324288);
  float* nsum = (float*)(ws + 13328384);
  unsigned* ecnt = (unsigned*)(ws + 13332480);
  unsigned* ncnt = (unsigned*)(ws + 13332512);

  // zero agg region (x_out part of d_out) and stat accumulators — every launch
  hipMemsetAsync(d_out, 0, (size_t)NN * DD * sizeof(float), stream);
  hipMemsetAsync(ws + 13324288, 0, 4096 + 4096 + 64, stream);

  wconv_kernel<<<256, 256, 0, stream>>>(eW1, wE1t, 512);
  wconv_kernel<<<64, 256, 0, stream>>>(eW2, wE2t, 128);
  wconv_kernel<<<64, 256, 0, stream>>>(eW3, wE3t, 128);
  wconv_kernel<<<192, 256, 0, stream>>>(nW1, wN1t, 384);
  wconv_kernel<<<64, 256, 0, stream>>>(nW2, wN2t, 128);
  wconv_kernel<<<64, 256, 0, stream>>>(nW3, wN3t, 128);
  xconv_kernel<<<6250, 256, 0, stream>>>(x, xbf, NN * DD / 4);

  edge_kernel<<<NE / 128, 256, 0, stream>>>(
      xbf, edge_attr, u, edge_index, batch,
      wE1t, wE2t, wE3t, eb1, eb2, eb3,
      edge_out, xout_agg, esum, ecnt);

  node_kernel<<<(NN + 127) / 128, 256, 0, stream>>>(
      xbf, xout_agg, u, batch,
      wN1t, wN2t, wN3t, nb1, nb2, nb3,
      nsum, ncnt);

  global_kernel<<<1, 256, 0, stream>>>(
      u, nsum, ncnt, esum, ecnt,
      gW1, gb1, gW2, gb2, gW3, gb3, u_out);
}